// Round 4
// baseline (146.373 us; speedup 1.0000x reference)
//
#include <hip/hip_runtime.h>
#include <stdint.h>

#define TPB 256
#define ROWS_PB 256
#define TC 256
#define CS 16

typedef unsigned long long u64;
typedef unsigned int u32;

__device__ __forceinline__ float waveReduceSum(float v){
#pragma unroll
  for (int o = 32; o > 0; o >>= 1) v += __shfl_down(v, o, 64);
  return v;
}

__device__ __forceinline__ float blockReduceSum(float v, float* buf4){
  v = waveReduceSum(v);
  __syncthreads();
  if ((threadIdx.x & 63) == 0) buf4[threadIdx.x >> 6] = v;
  __syncthreads();
  return buf4[0] + buf4[1] + buf4[2] + buf4[3];
}

// One direction of the chamfer/color min, expanded form d = rx + ry - 2<x,y>.
// LDS: [0,8K) = col tiles (float4 pts | float4 colors), reused as the u64
// cross-wave merge buffer after the last tile barrier; [8K,12K) = u32 merge.
// Results written as per-chunk partials (no atomics): part[chunk*BN + b*N + row].
template<bool NEED_IDX>
__device__ __forceinline__ void pass_body(
    const float* __restrict__ rows, const float* __restrict__ cols,
    void* __restrict__ outPart, u32* __restrict__ outColPart,
    char* lds, int N, int cpc, int BNtot)
{
  float4* ptsT = (float4*)lds;
  float4* colT = (float4*)(lds + 4096);
  u64* mPack   = (u64*)lds;            // reuse tiles after final barrier
  u32* mCol    = (u32*)(lds + 8192);

  const int b = blockIdx.y;
  const int rb = blockIdx.x / CS;
  const int chunk = blockIdx.x - rb * CS;
  const int t = threadIdx.x;
  const int lane = t & 63;
  const int w = t >> 6;
  const int rowBase = rb * ROWS_PB;
  const int colBase = chunk * cpc;

  float ax[4], ay[4], az[4], rx[4];
  float cr[4], cg[4], cbl[4], rc[4];
  float bD[4], bC[4];
  int bM[4];
#pragma unroll
  for (int k = 0; k < 4; k++){
    const float* p = rows + ((size_t)b * N + (rowBase + lane + 64 * k)) * 6;
    float p0 = p[0], p1 = p[1], p2 = p[2], p3 = p[3], p4 = p[4], p5 = p[5];
    ax[k] = -2.f * p0; ay[k] = -2.f * p1; az[k] = -2.f * p2;
    rx[k] = fmaf(p0, p0, fmaf(p1, p1, p2 * p2));
    cr[k] = -2.f * p3; cg[k] = -2.f * p4; cbl[k] = -2.f * p5;
    rc[k] = fmaf(p3, p3, fmaf(p4, p4, p5 * p5));
    bD[k] = 3.4e38f; bC[k] = 3.4e38f; bM[k] = 0;
  }

  for (int tb = 0; tb < cpc; tb += TC){
    const float* p = cols + ((size_t)b * N + (colBase + tb + t)) * 6;
    float q0 = p[0], q1 = p[1], q2 = p[2], q3 = p[3], q4 = p[4], q5 = p[5];
    ptsT[t] = make_float4(q0, q1, q2, fmaf(q0, q0, fmaf(q1, q1, q2 * q2)));
    colT[t] = make_float4(q3, q4, q5, fmaf(q3, q3, fmaf(q4, q4, q5 * q5)));
    __syncthreads();
#pragma unroll 4
    for (int j = 0; j < TC / 4; j += 2){
      const int mlA = j * 4 + w;
      const int mlB = mlA + 4;
      const float4 pA = ptsT[mlA], pB = ptsT[mlB];
      const float4 cA = colT[mlA], cB = colT[mlB];
      const int gA = colBase + tb + mlA;
      const int gB = gA + 4;
#pragma unroll
      for (int k = 0; k < 4; k++){
        float tA = fmaf(ax[k], pA.x, fmaf(ay[k], pA.y, fmaf(az[k], pA.z, pA.w)));
        float tB = fmaf(ax[k], pB.x, fmaf(ay[k], pB.y, fmaf(az[k], pB.z, pB.w)));
        if (NEED_IDX){
          if (tA < bD[k]) { bD[k] = tA; bM[k] = gA; }  // strict <, lower idx first
          if (tB < bD[k]) { bD[k] = tB; bM[k] = gB; }
        } else {
          bD[k] = fminf(fminf(tA, tB), bD[k]);
        }
        float eA = fmaf(cr[k], cA.x, fmaf(cg[k], cA.y, fmaf(cbl[k], cA.z, cA.w)));
        float eB = fmaf(cr[k], cB.x, fmaf(cg[k], cB.y, fmaf(cbl[k], cB.z, cB.w)));
        bC[k] = fminf(fminf(eA, eB), bC[k]);
      }
    }
    __syncthreads();
  }

#pragma unroll
  for (int k = 0; k < 4; k++){
    int r = lane + 64 * k;
    float dv = fmaxf(bD[k] + rx[k], 0.f);   // clamp: expanded form can round <0
    float cv = fmaxf(bC[k] + rc[k], 0.f);
    mPack[w * TPB + r] = NEED_IDX
        ? (((u64)__float_as_uint(dv) << 32) | (u32)bM[k])
        : (u64)__float_as_uint(dv);
    mCol[w * TPB + r] = __float_as_uint(cv);
  }
  __syncthreads();
  u64 pk = mPack[t];
  u32 cm = mCol[t];
#pragma unroll
  for (int i = 1; i < 4; i++){
    u64 p2 = mPack[i * TPB + t]; if (p2 < pk) pk = p2;
    u32 c2 = mCol[i * TPB + t];  if (c2 < cm) cm = c2;
  }
  size_t g = (size_t)chunk * BNtot + (size_t)b * N + rowBase + t;
  if (NEED_IDX) ((u64*)outPart)[g] = pk;
  else          ((u32*)outPart)[g] = (u32)pk;
  outColPart[g] = cm;
}

// Edge-independent partial sums (edge length L1, trunc(edge)^2 per channel),
// run as tail blocks of the big pass (no dependency on min results).
__device__ __forceinline__ void edge_partial(
    const float* __restrict__ preds, const int* __restrict__ edges,
    float* __restrict__ acc, int N, int E, int NXB)
{
  __shared__ float ebuf[4];
  int e = ((int)blockIdx.x - NXB) * TPB + threadIdx.x;
  int b = blockIdx.y;
  int e0 = edges[2 * e], e1 = edges[2 * e + 1];
  const float* p0 = preds + ((size_t)b * N + e0) * 6;
  const float* p1 = preds + ((size_t)b * N + e1) * 6;
  float ex = p0[0] - p1[0], ey = p0[1] - p1[1], ez = p0[2] - p1[2];
  float t0 = truncf(ex), t1 = truncf(ey), t2 = truncf(ez);
  float v[4] = { fabsf(ex) + fabsf(ey) + fabsf(ez), t0 * t0, t1 * t1, t2 * t2 };
#pragma unroll
  for (int q = 0; q < 4; q++){
    float s = blockReduceSum(v[q], ebuf);
    if (threadIdx.x == 0) atomicAdd(&acc[q == 0 ? 0 : 7 + b * 3 + (q - 1)], s);
  }
}

__global__ void __launch_bounds__(TPB, 8) pass_all(
    const float* __restrict__ gts, const float* __restrict__ preds,
    const int* __restrict__ edges,
    u64* __restrict__ packPart, u32* __restrict__ distPart,
    u32* __restrict__ colPart2, u32* __restrict__ colPart1,
    float* __restrict__ acc, int N, int cpc, int NXB, int E, int BNtot)
{
  __shared__ __align__(16) char lds[12288];
  if ((int)blockIdx.x >= NXB){
    if (blockIdx.z == 0) edge_partial(preds, edges, acc, N, E, NXB);
    return;
  }
  if (blockIdx.z == 0) pass_body<true >(gts,  preds, packPart, colPart2, lds, N, cpc, BNtot);
  else                 pass_body<false>(preds, gts,  distPart, colPart1, lds, N, cpc, BNtot);
}

// acc: [0]=edge_len sum, [1..6]=Sn[b][c], [7..12]=Se[b][c], [13]=cos sum,
//      [14]=weighted min sum, [15]=completion counter (u32)
// blocks [0,nRowBlk): reduce chunk partials per row + weighted sum.
// blocks [nRowBlk,..): per-edge idx (re-reduced from partials) -> Sn[b][c].
__global__ void __launch_bounds__(TPB) mid_kernel(
    const u64* __restrict__ packPart, const u32* __restrict__ distPart,
    const u32* __restrict__ colPart2, const u32* __restrict__ colPart1,
    const float* __restrict__ normals, const int* __restrict__ edges,
    float* __restrict__ acc, int N, int E, int BNtot, int nRowBlk)
{
  __shared__ float buf4[4];
  if ((int)blockIdx.x < nRowBlk){
    int row = blockIdx.x * TPB + threadIdx.x;   // BNtot == nRowBlk*TPB
    u64 pk = packPart[row];
    u32 f2 = distPart[row], c2 = colPart2[row], c1 = colPart1[row];
#pragma unroll
    for (int c = 1; c < CS; c++){
      size_t o = (size_t)c * BNtot + row;
      u64 p = packPart[o]; if (p < pk) pk = p;
      u32 d = distPart[o]; if (d < f2) f2 = d;
      u32 x2 = colPart2[o]; if (x2 < c2) c2 = x2;
      u32 x1 = colPart1[o]; if (x1 < c1) c1 = x1;
    }
    float invN = 1.f / (float)N;
    float s = 3000.f * invN * __uint_as_float(f2)
            + 1650.f * invN * __uint_as_float((u32)(pk >> 32))
            + __uint_as_float(c1) + __uint_as_float(c2);
    s = blockReduceSum(s, buf4);
    if (threadIdx.x == 0) atomicAdd(&acc[14], s);
  } else {
    int gid = ((int)blockIdx.x - nRowBlk) * TPB + threadIdx.x;
    int b = gid / E, e = gid - b * E;            // E%TPB==0 -> block-uniform b
    int e0 = edges[2 * e];
    size_t r = (size_t)b * N + e0;
    u64 pk = packPart[r];
#pragma unroll
    for (int c = 1; c < CS; c++){
      u64 p = packPart[(size_t)c * BNtot + r]; if (p < pk) pk = p;
    }
    const float* nr = normals + ((size_t)b * N + (u32)pk) * 3;
    float n0 = nr[0], n1 = nr[1], n2 = nr[2];
    float s0 = blockReduceSum(n0 * n0, buf4);
    if (threadIdx.x == 0) atomicAdd(&acc[1 + b * 3 + 0], s0);
    float s1 = blockReduceSum(n1 * n1, buf4);
    if (threadIdx.x == 0) atomicAdd(&acc[1 + b * 3 + 1], s1);
    float s2 = blockReduceSum(n2 * n2, buf4);
    if (threadIdx.x == 0) atomicAdd(&acc[1 + b * 3 + 2], s2);
  }
}

// Cosine pass + final combine in the last finishing block (atomic counter).
__global__ void __launch_bounds__(TPB) edge_cos_kernel(
    const float* __restrict__ preds, const float* __restrict__ normals,
    const int* __restrict__ edges, const u64* __restrict__ packPart,
    float* __restrict__ acc, float* __restrict__ out,
    int N, int E, int BNtot, int nBlocks)
{
  __shared__ float buf4[4];
  int gid = blockIdx.x * TPB + threadIdx.x;
  int b = gid / E, e = gid - b * E;
  int e0 = edges[2 * e], e1 = edges[2 * e + 1];
  const float* p0 = preds + ((size_t)b * N + e0) * 6;
  const float* p1 = preds + ((size_t)b * N + e1) * 6;
  float ex = p0[0] - p1[0], ey = p0[1] - p1[1], ez = p0[2] - p1[2];
  float t0 = truncf(ex), t1 = truncf(ey), t2 = truncf(ez);
  size_t r = (size_t)b * N + e0;
  u64 pk = packPart[r];
#pragma unroll
  for (int c = 1; c < CS; c++){
    u64 p = packPart[(size_t)c * BNtot + r]; if (p < pk) pk = p;
  }
  const float* nr = normals + ((size_t)b * N + (u32)pk) * 3;
  // _unit_axis1 normalizes over the E axis: per (b,channel) norms
  float r0 = 1.f / (fmaxf(sqrtf(acc[1 + b * 3 + 0]), 1e-12f) * fmaxf(sqrtf(acc[7 + b * 3 + 0]), 1e-12f));
  float r1 = 1.f / (fmaxf(sqrtf(acc[1 + b * 3 + 1]), 1e-12f) * fmaxf(sqrtf(acc[7 + b * 3 + 1]), 1e-12f));
  float r2 = 1.f / (fmaxf(sqrtf(acc[1 + b * 3 + 2]), 1e-12f) * fmaxf(sqrtf(acc[7 + b * 3 + 2]), 1e-12f));
  float cosv = fabsf(nr[0] * t0 * r0 + nr[1] * t1 * r1 + nr[2] * t2 * r2);
  float s = blockReduceSum(cosv, buf4);
  if (threadIdx.x == 0){
    atomicAdd(&acc[13], s);
    __threadfence();
    u32 old = atomicAdd((u32*)&acc[15], 1u);
    if (old == (u32)(nBlocks - 1)){
      // last block: all adds visible; read through atomics (bypass stale L1)
      float a0  = atomicAdd(&acc[0],  0.f);
      float a13 = atomicAdd(&acc[13], 0.f);
      float a14 = atomicAdd(&acc[14], 0.f);
      out[0] = a14 + a0 * (300.f / (float)E) + a13 * (0.5f / (float)E);
    }
  }
}

extern "C" void kernel_launch(void* const* d_in, const int* in_sizes, int n_in,
                              void* d_out, int out_size, void* d_ws, size_t ws_size,
                              hipStream_t stream)
{
  const float* gts     = (const float*)d_in[0];
  const float* preds   = (const float*)d_in[1];
  const float* normals = (const float*)d_in[2];
  const int*   edges   = (const int*)d_in[3];

  const int B = 2;
  const int BNtot = in_sizes[2] / 3;   // B*N from gts_normals
  const int N = BNtot / B;
  const int E = in_sizes[3] / 2;

  char* ws = (char*)d_ws;
  size_t nPart = (size_t)CS * BNtot;
  u64* packPart = (u64*)ws;                                   // CS*BN u64
  u32* distPart = (u32*)(ws + nPart * 8);                     // CS*BN u32
  u32* colPart2 = (u32*)(ws + nPart * 12);                    // CS*BN u32
  u32* colPart1 = (u32*)(ws + nPart * 16);                    // CS*BN u32
  float* acc    = (float*)(ws + nPart * 20);                  // 16 f32

  hipMemsetAsync(acc, 0, 64, stream);

  int cpc = N / CS;
  int NXB = (N / ROWS_PB) * CS;
  int nEdgeBlk = (B * E) / (TPB * B);      // E/TPB per batch, y carries b
  dim3 gp(NXB + nEdgeBlk, B, 2);
  pass_all<<<gp, TPB, 0, stream>>>(gts, preds, edges, packPart, distPart,
                                   colPart2, colPart1, acc, N, cpc, NXB, E, BNtot);

  int nRowBlk = BNtot / TPB;
  int nMid = nRowBlk + (B * E) / TPB;
  mid_kernel<<<nMid, TPB, 0, stream>>>(packPart, distPart, colPart2, colPart1,
                                       normals, edges, acc, N, E, BNtot, nRowBlk);

  int nCos = (B * E) / TPB;
  edge_cos_kernel<<<nCos, TPB, 0, stream>>>(preds, normals, edges, packPart,
                                            acc, (float*)d_out, N, E, BNtot, nCos);
}